// Round 12
// baseline (1406.875 us; speedup 1.0000x reference)
//
#include <hip/hip_runtime.h>

#define B_    32
#define SSRC  128
#define STGT  64
#define E_    256
#define H_    512
#define G4    2048
#define V_    32000

typedef unsigned short u16;
typedef short bf16x8 __attribute__((ext_vector_type(8)));
typedef float f32x4 __attribute__((ext_vector_type(4)));

__device__ __forceinline__ u16 f2b(float f) {
  unsigned u = __float_as_uint(f);
  u += 0x7FFFu + ((u >> 16) & 1u);
  return (u16)(u >> 16);
}
__device__ __forceinline__ float b2f(u16 h) {
  return __uint_as_float(((unsigned)h) << 16);
}
__device__ __forceinline__ unsigned pk2(float lo, float hi) {
  return (unsigned)f2b(lo) | (((unsigned)f2b(hi)) << 16);
}
__device__ __forceinline__ float sigm(float x) { return 1.0f / (1.0f + __expf(-x)); }
__device__ __forceinline__ float tanh_(float x) { return 1.0f - 2.0f / (1.0f + __expf(2.0f * x)); }

#if defined(__has_builtin)
#if __has_builtin(__builtin_amdgcn_fdot2_f32_bf16)
#define HAS_DOT2 1
#endif
#endif
#ifdef HAS_DOT2
typedef __bf16 b162 __attribute__((ext_vector_type(2)));
__device__ __forceinline__ float dot2u(unsigned a, unsigned b, float acc) {
  return __builtin_amdgcn_fdot2_f32_bf16(__builtin_bit_cast(b162, a),
                                         __builtin_bit_cast(b162, b), acc, false);
}
#else
__device__ __forceinline__ float dot2u(unsigned a, unsigned b, float acc) {
  acc += __uint_as_float(a << 16) * __uint_as_float(b << 16);
  acc += __uint_as_float(a & 0xffff0000u) * __uint_as_float(b & 0xffff0000u);
  return acc;
}
#endif
__device__ __forceinline__ float dot4(uint4 w, uint4 h, float acc) {
  return dot2u(w.w, h.w, dot2u(w.z, h.z, dot2u(w.y, h.y, dot2u(w.x, h.x, acc))));
}

__device__ __forceinline__ int swz64(int c) {
  return (c & ~3) | ((c & 3) ^ ((c >> 3) & 3));
}

// ---- device-coherent accesses ----
__device__ __forceinline__ uint4 cload4(const void* p) {
  uint4 r;
  asm volatile("global_load_dwordx4 %0, %1, off sc0 sc1\n\ts_waitcnt vmcnt(0)"
               : "=&v"(r) : "v"(p) : "memory");
  return r;
}
__device__ __forceinline__ void cstoref(float* p, float v) {
  asm volatile("global_store_dword %0, %1, off sc0 sc1" :: "v"(p), "v"(v) : "memory");
}
__device__ __forceinline__ void cstoreu(unsigned* p, unsigned v) {
  asm volatile("global_store_dword %0, %1, off sc0 sc1" :: "v"(p), "v"(v) : "memory");
}
__device__ __forceinline__ float cloadf_relaxed(const float* p) {
  return __hip_atomic_load(p, __ATOMIC_RELAXED, __HIP_MEMORY_SCOPE_AGENT);
}

// ---- split barrier: arrive (drain stores + flag) ... optional shadow ... wait ----
__device__ __forceinline__ void arrive(int* flags, int myid, int target) {
  asm volatile("s_waitcnt vmcnt(0)" ::: "memory");
  __syncthreads();
  if (threadIdx.x == 0)
    __hip_atomic_store(flags + myid, target, __ATOMIC_RELAXED, __HIP_MEMORY_SCOPE_AGENT);
}
__device__ __forceinline__ void waitbar(int* flags, int target) {
  if (threadIdx.x < 64) {
    int l = threadIdx.x & 31;
    while (__hip_atomic_load(flags + l, __ATOMIC_RELAXED, __HIP_MEMORY_SCOPE_AGENT) < target)
      __builtin_amdgcn_s_sleep(1);
  }
  __syncthreads();
  asm volatile("" ::: "memory");
}

// ---- fused poll + group-h load: wave 0 polls flags, then immediately loads the
// whole group's h (4x dwordx4/lane, single vmcnt) into LDS. Other waves park at
// the closing syncthreads — removes the wake->issue round trip.
__device__ __forceinline__ void waitload_h(int* flags, int target,
                                           const unsigned* hd, int b0, uint4* hl16) {
  const int tid = threadIdx.x;
  if (tid < 64) {
    int l = tid & 31;
    while (__hip_atomic_load(flags + l, __ATOMIC_RELAXED, __HIP_MEMORY_SCOPE_AGENT) < target)
      __builtin_amdgcn_s_sleep(1);
    const uint4* src = (const uint4*)hd + (size_t)b0 * 64;
    int row = tid >> 4;         // 0..3
    int c0 = (tid & 15) * 4;    // 0,4,...,60
    const uint4* p0 = src + row * 64 + c0;
    uint4 a, b, c, d;
    asm volatile(
        "global_load_dwordx4 %0, %4, off sc0 sc1\n\t"
        "global_load_dwordx4 %1, %5, off sc0 sc1\n\t"
        "global_load_dwordx4 %2, %6, off sc0 sc1\n\t"
        "global_load_dwordx4 %3, %7, off sc0 sc1\n\t"
        "s_waitcnt vmcnt(0)"
        : "=&v"(a), "=&v"(b), "=&v"(c), "=&v"(d)
        : "v"(p0), "v"(p0 + 1), "v"(p0 + 2), "v"(p0 + 3)
        : "memory");
    hl16[row * 64 + swz64(c0 + 0)] = a;
    hl16[row * 64 + swz64(c0 + 1)] = b;
    hl16[row * 64 + swz64(c0 + 2)] = c;
    hl16[row * 64 + swz64(c0 + 3)] = d;
  }
  __syncthreads();
  asm volatile("" ::: "memory");
}

// ---------------- prep: gathers + bf16 conversions ----------------
__global__ void prep_kernel(const int* __restrict__ src, const int* __restrict__ tgt,
                            const float* __restrict__ enc_emb, const float* __restrict__ dec_emb,
                            const float* __restrict__ enc_Wih, const float* __restrict__ dec_Wih,
                            const float* __restrict__ attn_W, const float* __restrict__ out_W,
                            u16* __restrict__ A_enc, u16* __restrict__ A_dec,
                            u16* __restrict__ WihE, u16* __restrict__ WihD,
                            u16* __restrict__ Web, u16* __restrict__ WihCp,
                            u16* __restrict__ outWb)
{
  const long n_outw = (long)V_ * H_;
  const long n_aenc = (long)B_ * SSRC * E_;
  const long n_adec = (long)B_ * STGT * E_;
  const long n_wih  = (long)G4 * E_;
  const long n_web  = (long)H_ * H_;
  const long n_wcp  = (long)G4 * H_;
  const long total = n_outw + n_aenc + n_adec + 2 * n_wih + n_web + n_wcp;
  for (long i = (long)blockIdx.x * blockDim.x + threadIdx.x; i < total;
       i += (long)gridDim.x * blockDim.x) {
    long x = i;
    if (x < n_outw) { outWb[x] = f2b(out_W[x]); continue; }
    x -= n_outw;
    if (x < n_aenc) {
      int row = (int)(x >> 8), e = (int)(x & 255);
      A_enc[x] = f2b(enc_emb[(size_t)src[row] * E_ + e]);
      continue;
    }
    x -= n_aenc;
    if (x < n_adec) {
      int row = (int)(x >> 8), e = (int)(x & 255);
      A_dec[x] = f2b(dec_emb[(size_t)tgt[row] * E_ + e]);
      continue;
    }
    x -= n_adec;
    if (x < n_wih) { WihE[x] = f2b(enc_Wih[x]); continue; }
    x -= n_wih;
    if (x < n_wih) {
      int r = (int)(x >> 8), e = (int)(x & 255);
      WihD[x] = f2b(dec_Wih[(size_t)r * 768 + e]);
      continue;
    }
    x -= n_wih;
    if (x < n_web) {
      int d = (int)(x >> 9), k = (int)(x & 511);
      Web[x] = f2b(attn_W[(size_t)d * 1024 + 512 + k]);
      continue;
    }
    x -= n_web;
    {
      // permuted WihC rows: n = gb*64 + gate*16 + jl  ->  orig gate*512 + gb*16 + jl
      int n = (int)(x >> 9), k = (int)(x & 511);
      int gb = n >> 6, gate = (n >> 4) & 3, jl = n & 15;
      int orig = gate * 512 + gb * 16 + jl;
      WihCp[x] = f2b(dec_Wih[(size_t)orig * 768 + 256 + k]);
    }
  }
}

// ---------------- NT GEMM: C[m][n] = sum_k A[m][k]*B[n][k] + bias[n] ----------------
// XCD-bijective block swizzle (grid % 8 == 0 for all call sites): contiguous
// chunk of block-ids per XCD -> B panels land in exactly one XCD L2.
template<int KTOT, bool OBF>
__global__ __launch_bounds__(256, 2) void gemm_nt(
    const u16* __restrict__ A, const u16* __restrict__ Bm,
    const float* __restrict__ bias, void* __restrict__ Cv, int M, int N)
{
  int nid = ((blockIdx.x & 7) * (gridDim.x >> 3)) + (blockIdx.x >> 3);
  int nbm = M >> 7;
  int bn = nid / nbm;
  int bm = nid % nbm;
  int w = threadIdx.x >> 6, l = threadIdx.x & 63;
  int wr = w >> 1, wc = w & 1;
  int m0 = bm * 128 + wr * 64, n0 = bn * 128 + wc * 64;
  int lr = l & 15, ko = (l >> 4) * 8;
  f32x4 acc[4][4] = {};
  const u16* Ap = A + (size_t)(m0 + lr) * KTOT + ko;
  const u16* Bp = Bm + (size_t)(n0 + lr) * KTOT + ko;
  for (int k0 = 0; k0 < KTOT; k0 += 32) {
    bf16x8 af[4], bfr[4];
#pragma unroll
    for (int i = 0; i < 4; ++i) af[i] = *(const bf16x8*)(Ap + (size_t)i * 16 * KTOT + k0);
#pragma unroll
    for (int i = 0; i < 4; ++i) bfr[i] = *(const bf16x8*)(Bp + (size_t)i * 16 * KTOT + k0);
#pragma unroll
    for (int i = 0; i < 4; ++i)
#pragma unroll
      for (int j = 0; j < 4; ++j)
        acc[i][j] = __builtin_amdgcn_mfma_f32_16x16x32_bf16(af[i], bfr[j], acc[i][j], 0, 0, 0);
  }
  int rbase = (l >> 4) * 4;
#pragma unroll
  for (int i = 0; i < 4; ++i) {
#pragma unroll
    for (int j = 0; j < 4; ++j) {
      int gn = n0 + j * 16 + lr;
      float bv = bias ? bias[gn] : 0.f;
#pragma unroll
      for (int r = 0; r < 4; ++r) {
        int gm = m0 + i * 16 + rbase + r;
        float v = acc[i][j][r] + bv;
        if (OBF) ((u16*)Cv)[(size_t)gm * N + gn] = f2b(v);
        else     ((float*)Cv)[(size_t)gm * N + gn] = v;
      }
    }
  }
}

// ---- shared z-GEMV: 64 gate-rows x 512 k, bf16, swizzled LDS ----
__device__ __forceinline__ void zgemv64(int tid, const uint4* Wu, const uint4* Hu,
                                        float (*part)[64][4]) {
  int rq = tid >> 4, kq = tid & 15;
  float acc[4][4] = {};
#pragma unroll
  for (int u = 0; u < 4; ++u) {
    int sc = swz64(kq * 4 + u);
    uint4 h0 = Hu[sc], h1 = Hu[64 + sc], h2 = Hu[128 + sc], h3 = Hu[192 + sc];
#pragma unroll
    for (int r = 0; r < 4; ++r) {
      uint4 wv = Wu[(rq * 4 + r) * 64 + sc];
      acc[r][0] = dot4(wv, h0, acc[r][0]);
      acc[r][1] = dot4(wv, h1, acc[r][1]);
      acc[r][2] = dot4(wv, h2, acc[r][2]);
      acc[r][3] = dot4(wv, h3, acc[r][3]);
    }
  }
#pragma unroll
  for (int r = 0; r < 4; ++r) {
    float4 v = {acc[r][0], acc[r][1], acc[r][2], acc[r][3]};
    *(float4*)&part[kq][(rq * 4 + r) ^ (kq & 7)][0] = v;
  }
}

template<typename GrowF>
__device__ __forceinline__ void fillw64(int tid, const float* Wsrc, uint4* Wu, GrowF grow) {
#pragma unroll 4
  for (int i = 0; i < 16; ++i) {
    int idx4 = tid + i * 256;
    int row = idx4 >> 6, c = idx4 & 63;
    const float* s = Wsrc + (size_t)grow(row) * 512 + c * 8;
    float4 a = *(const float4*)s, b4 = *(const float4*)(s + 4);
    uint4 pkv = {pk2(a.x, a.y), pk2(a.z, a.w), pk2(b4.x, b4.y), pk2(b4.z, b4.w)};
    Wu[row * 64 + swz64(c)] = pkv;
  }
}

// ---------------- encoder: persistent, 8 groups x 32 blocks, 1 fused barrier/step --
__global__ __launch_bounds__(256, 1) void encoder_kernel(
    const float* __restrict__ enc_Whh, const u16* __restrict__ encXW,
    unsigned* __restrict__ h16buf /* u32 [2][32][256] */,
    float* __restrict__ cfin, u16* __restrict__ eo_g, int* __restrict__ bars)
{
  const int tid = threadIdx.x;
  const int g = blockIdx.x & 7;
  const int gb = blockIdx.x >> 3;
  const int b0 = g * 4;
  const int ds0 = gb * 16;
  int* flags = bars + g * 64;

  __shared__ uint4 encW4[64 * 64];   // 64 KB
  __shared__ uint4 hl16[4 * 64];     // 4 KB
  __shared__ float part[16][64][4];  // 16 KB
  __shared__ float zx[4][64];
  __shared__ float cS[4][16];

  if (tid < 64) cS[tid >> 4][tid & 15] = 0.f;
  fillw64(tid, enc_Whh, encW4, [&](int row) { return (row >> 4) * 512 + ds0 + (row & 15); });

  const int bl_c = tid >> 6, rl_c = tid & 63;
  const int grow_c = (rl_c >> 4) * 512 + ds0 + (rl_c & 15);
  const u16* xwp = encXW + (size_t)(b0 + bl_c) * SSRC * G4 + grow_c;

  // prologue: h(0) (zeros from memset) + xw(0)
  {
    int row = tid >> 6, c = tid & 63;
    uint4 v = cload4((const uint4*)h16buf + (b0 + row) * 64 + c);
    hl16[row * 64 + swz64(c)] = v;
  }
  u16 xw = xwp[0];
  __syncthreads();

  for (int t = 0; t < SSRC; ++t) {
    zgemv64(tid, encW4, hl16, part);
    __syncthreads();
    {
      float z = 0.f;
#pragma unroll
      for (int kq = 0; kq < 16; ++kq) z += part[kq][rl_c ^ (kq & 7)][bl_c];
      z += b2f(xw);
      zx[bl_c][rl_c] = z;
    }
    __syncthreads();
    if (tid < 64) {
      int bl = tid >> 4, jl = tid & 15;
      float iv = zx[bl][jl], fv = zx[bl][16 + jl], gv = zx[bl][32 + jl], ov = zx[bl][48 + jl];
      float cn = sigm(fv) * cS[bl][jl] + sigm(iv) * tanh_(gv);
      float hn = sigm(ov) * tanh_(cn);
      cS[bl][jl] = cn;
      eo_g[((size_t)(b0 + bl) * SSRC + t) * H_ + ds0 + jl] = f2b(hn);
      float hn1 = __shfl_down(hn, 1);
      if ((jl & 1) == 0)
        cstoreu(h16buf + (size_t)((t + 1) & 1) * 8192 + (size_t)(b0 + bl) * 256 + gb * 8 + (jl >> 1),
                pk2(hn, hn1));
    }
    if (t < SSRC - 1) {
      arrive(flags, gb, t + 1);
      xw = xwp[(size_t)(t + 1) * G4];  // prefetch in barrier shadow
      waitload_h(flags, t + 1, h16buf + (size_t)((t + 1) & 1) * 8192, b0, hl16);
    }
    // t == SSRC-1: final h published to buffer 0 for decoder; kernel end syncs.
  }
  if (tid < 64)
    cfin[(size_t)(b0 + (tid >> 4)) * H_ + ds0 + (tid & 15)] = cS[tid >> 4][tid & 15];
}

// ---------------- decoder: persistent, 2 barriers/step (1 shadowed, 1 fused) -------
__global__ __launch_bounds__(256, 1) void decoder_kernel(
    const float* __restrict__ dec_Whh, const float* __restrict__ attn_W,
    const float* __restrict__ attn_b, const float* __restrict__ attn_v,
    const u16* __restrict__ eprojb, const u16* __restrict__ decXW,
    const u16* __restrict__ eoPb,
    unsigned* __restrict__ hd16, const float* __restrict__ cfin,
    float* __restrict__ vpart /* f32 [8*32][512] */,
    u16* __restrict__ dech, int* __restrict__ bars)
{
  const int tid = threadIdx.x;
  const int g = blockIdx.x & 7;
  const int gb = blockIdx.x >> 3;
  const int b0 = g * 4;
  const int ds0 = gb * 16;
  int* flags = bars + g * 64;
  int ep_ = 0;

  __shared__ uint4 decW4[64 * 64];   // 64 KB
  __shared__ uint4 Whb4[16 * 64];    // 16 KB
  __shared__ uint4 epL[512][2];      // 16 KB (step-invariant eproj slice)
  __shared__ uint4 hl16[4 * 64];     // 4 KB
  __shared__ float part[16][64][4];  // 16 KB
  __shared__ float partE[8][64][4];  // 8 KB
  __shared__ float scoreS[4][128];   // 2 KB
  __shared__ float aS[4][128];       // 2 KB
  __shared__ float zx[4][64];
  __shared__ float qS[4][16];
  __shared__ float cS[4][16];
  __shared__ float vS[16], bS[16];

  if (tid < 64) cS[tid >> 4][tid & 15] = cfin[(size_t)(b0 + (tid >> 4)) * H_ + ds0 + (tid & 15)];
  if (tid < 16) { vS[tid] = attn_v[ds0 + tid]; bS[tid] = attn_b[ds0 + tid]; }
  fillw64(tid, dec_Whh, decW4, [&](int row) { return (row >> 4) * 512 + ds0 + (row & 15); });
#pragma unroll
  for (int i = 0; i < 4; ++i) {
    int idx4 = tid + i * 256;
    int row = idx4 >> 6, c = idx4 & 63;
    const float* s = attn_W + (size_t)(ds0 + row) * 1024 + c * 8;
    float4 a = *(const float4*)s, b4 = *(const float4*)(s + 4);
    uint4 pkv = {pk2(a.x, a.y), pk2(a.z, a.w), pk2(b4.x, b4.y), pk2(b4.z, b4.w)};
    Whb4[row * 64 + (c ^ (row & 7))] = pkv;
  }
  // eproj slice -> LDS once (step-invariant)
#pragma unroll
  for (int r = 0; r < 2; ++r) {
    int idx = tid + r * 256;
    int b_l = idx >> 7, s = idx & 127;
    const uint4* ep = (const uint4*)(eprojb + (((size_t)(b0 + b_l) * SSRC + s) << 9) + ds0);
    epL[idx][0] = ep[0];
    epL[idx][1] = ep[1];
  }
  // ---- preload this block's static eoP slice into registers (64 KB/block) ----
  // eoPb columns PERMUTED (WihCp): this block's slice = u32 range [gb*32, gb*32+32).
  const int sq = tid >> 5, cp = tid & 31;
  const int n32 = gb * 32 + cp;
  uint4 eor[16];
  {
    const unsigned* eoPu = (const unsigned*)eoPb;
#pragma unroll
    for (int si = 0; si < 16; ++si) {
      int s = sq * 16 + si;
      eor[si].x = eoPu[((size_t)(b0 + 0) * SSRC + s) * 1024 + n32];
      eor[si].y = eoPu[((size_t)(b0 + 1) * SSRC + s) * 1024 + n32];
      eor[si].z = eoPu[((size_t)(b0 + 2) * SSRC + s) * 1024 + n32];
      eor[si].w = eoPu[((size_t)(b0 + 3) * SSRC + s) * 1024 + n32];
    }
  }

  const int bl_c = tid >> 6, rl_c = tid & 63;
  const int grow_c = (rl_c >> 4) * 512 + ds0 + (rl_c & 15);
  const u16* xwp = decXW + (size_t)(b0 + bl_c) * STGT * G4 + grow_c;

  // prologue: h(0) from encoder handoff (kernel boundary syncs) + xw(0)
  {
    int row = tid >> 6, c = tid & 63;
    uint4 v = cload4((const uint4*)hd16 + (b0 + row) * 64 + c);
    hl16[row * 64 + swz64(c)] = v;
  }
  u16 xw = xwp[0];
  __syncthreads();

  for (int t = 0; t < STGT; ++t) {
    // ==== Phase 1: local q-slice; energy d-partials; publish; shadow=zgemv ====
    {
      int b_l = tid >> 6, d_l = (tid >> 2) & 15, kq4 = tid & 3;
      float acc = 0.f;
#pragma unroll
      for (int u = 0; u < 16; ++u) {
        int c = kq4 * 16 + u;
        acc = dot4(Whb4[d_l * 64 + (c ^ (d_l & 7))], hl16[b_l * 64 + swz64(c)], acc);
      }
      acc += __shfl_xor(acc, 1);
      acc += __shfl_xor(acc, 2);
      if (kq4 == 0) qS[b_l][d_l] = acc + bS[d_l];
    }
    __syncthreads();
    {
      float* vp = vpart + ((size_t)g * 32 + gb) * 512;
#pragma unroll
      for (int r = 0; r < 2; ++r) {
        int idx = tid + r * 256;
        int b_l = idx >> 7;
        uint4 e0 = epL[idx][0], e1 = epL[idx][1];
        float acc = 0.f;
        acc += vS[0]  * tanh_(b2f((u16)(e0.x & 0xffff)) + qS[b_l][0]);
        acc += vS[1]  * tanh_(b2f((u16)(e0.x >> 16))    + qS[b_l][1]);
        acc += vS[2]  * tanh_(b2f((u16)(e0.y & 0xffff)) + qS[b_l][2]);
        acc += vS[3]  * tanh_(b2f((u16)(e0.y >> 16))    + qS[b_l][3]);
        acc += vS[4]  * tanh_(b2f((u16)(e0.z & 0xffff)) + qS[b_l][4]);
        acc += vS[5]  * tanh_(b2f((u16)(e0.z >> 16))    + qS[b_l][5]);
        acc += vS[6]  * tanh_(b2f((u16)(e0.w & 0xffff)) + qS[b_l][6]);
        acc += vS[7]  * tanh_(b2f((u16)(e0.w >> 16))    + qS[b_l][7]);
        acc += vS[8]  * tanh_(b2f((u16)(e1.x & 0xffff)) + qS[b_l][8]);
        acc += vS[9]  * tanh_(b2f((u16)(e1.x >> 16))    + qS[b_l][9]);
        acc += vS[10] * tanh_(b2f((u16)(e1.y & 0xffff)) + qS[b_l][10]);
        acc += vS[11] * tanh_(b2f((u16)(e1.y >> 16))    + qS[b_l][11]);
        acc += vS[12] * tanh_(b2f((u16)(e1.z & 0xffff)) + qS[b_l][12]);
        acc += vS[13] * tanh_(b2f((u16)(e1.z >> 16))    + qS[b_l][13]);
        acc += vS[14] * tanh_(b2f((u16)(e1.w & 0xffff)) + qS[b_l][14]);
        acc += vS[15] * tanh_(b2f((u16)(e1.w >> 16))    + qS[b_l][15]);
        cstoref(vp + idx, acc);
      }
    }
    arrive(flags, gb, ++ep_);
    zgemv64(tid, decW4, hl16, part);   // shadow: hides vpart exchange flight
    waitbar(flags, ep_);

    // ==== Phase 2: gather partials -> scores; softmax; eoP-reg z; gates ====
    {
      int b_l = tid >> 6, s0 = (tid & 63) * 2;
      float a0 = 0.f, a1 = 0.f;
#pragma unroll 8
      for (int j = 0; j < 32; ++j) {
        const float* p = vpart + ((size_t)g * 32 + j) * 512 + b_l * 128 + s0;
        a0 += cloadf_relaxed(p);
        a1 += cloadf_relaxed(p + 1);
      }
      scoreS[b_l][s0] = a0;
      scoreS[b_l][s0 + 1] = a1;
    }
    __syncthreads();
    {
      int w = tid >> 6, lane = tid & 63;
      float s1 = scoreS[w][lane], s2v = scoreS[w][64 + lane];
      float m = fmaxf(s1, s2v);
#pragma unroll
      for (int off = 32; off; off >>= 1) m = fmaxf(m, __shfl_xor(m, off));
      float e1 = __expf(s1 - m), e2 = __expf(s2v - m);
      float sm = e1 + e2;
#pragma unroll
      for (int off = 32; off; off >>= 1) sm += __shfl_xor(sm, off);
      float inv = 1.0f / sm;
      aS[w][lane] = e1 * inv;
      aS[w][64 + lane] = e2 * inv;
    }
    __syncthreads();
    {
      float a0 = 0.f, a1 = 0.f, a2 = 0.f, a3 = 0.f, a4 = 0.f, a5 = 0.f, a6 = 0.f, a7 = 0.f;
#pragma unroll
      for (int si = 0; si < 16; ++si) {
        int s = sq * 16 + si;
        float w0 = aS[0][s], w1 = aS[1][s], w2 = aS[2][s], w3 = aS[3][s];
        unsigned u0 = eor[si].x, u1 = eor[si].y, u2 = eor[si].z, u3 = eor[si].w;
        a0 += w0 * b2f((u16)(u0 & 0xffff)); a1 += w0 * b2f((u16)(u0 >> 16));
        a2 += w1 * b2f((u16)(u1 & 0xffff)); a3 += w1 * b2f((u16)(u1 >> 16));
        a4 += w2 * b2f((u16)(u2 & 0xffff)); a5 += w2 * b2f((u16)(u2 >> 16));
        a6 += w3 * b2f((u16)(u3 & 0xffff)); a7 += w3 * b2f((u16)(u3 >> 16));
      }
      int r0 = cp * 2;  // permuted layout (r7 pairing)
      float4 lo = {a0, a2, a4, a6}, hi = {a1, a3, a5, a7};
      *(float4*)&partE[sq][r0][0] = lo;
      *(float4*)&partE[sq][r0 + 1][0] = hi;
    }
    __syncthreads();
    {
      float z = 0.f;
#pragma unroll
      for (int kq = 0; kq < 16; ++kq) z += part[kq][rl_c ^ (kq & 7)][bl_c];
#pragma unroll
      for (int sq2 = 0; sq2 < 8; ++sq2) z += partE[sq2][rl_c][bl_c];
      z += b2f(xw);
      zx[bl_c][rl_c] = z;
    }
    __syncthreads();
    if (tid < 64) {
      int bl = tid >> 4, jl = tid & 15;
      float iv = zx[bl][jl], fv = zx[bl][16 + jl], gv = zx[bl][32 + jl], ov = zx[bl][48 + jl];
      float cn = sigm(fv) * cS[bl][jl] + sigm(iv) * tanh_(gv);
      float hn = sigm(ov) * tanh_(cn);
      cS[bl][jl] = cn;
      dech[((size_t)(b0 + bl) * STGT + t) * H_ + ds0 + jl] = f2b(hn);
      float hn1 = __shfl_down(hn, 1);
      if ((jl & 1) == 0)
        cstoreu(hd16 + (size_t)(b0 + bl) * 256 + gb * 8 + (jl >> 1), pk2(hn, hn1));
    }
    if (t < STGT - 1) {
      arrive(flags, gb, ++ep_);
      xw = xwp[(size_t)(t + 1) * G4];  // prefetch in barrier shadow
      waitload_h(flags, ep_, hd16, b0, hl16);
    }
  }
}

// ---------------- workspace layout (bytes) ----------------
#define OFF_BARE   0u
#define OFF_BARD   2048u
#define OFF_H16    4096u        // u32 [2][32][256] = 64 KB
#define OFF_CFIN   69632u       // 64 KB
#define OFF_VPART  135168u      // f32 [256][512] = 512 KB
#define OFF_AENC   659456u      // 2 MB
#define OFF_ADEC   2756608u     // 1 MB
#define OFF_WIHE   3805184u     // 1 MB
#define OFF_WIHD   4853760u     // 1 MB
#define OFF_WEB    5902336u     // 512 KB
#define OFF_WIHCP  6426624u     // 2 MB
#define OFF_OUTW   8523776u     // 32.77 MB
#define OFF_ENCXW  41291776u    // 16.78 MB  [aliased by eoP after encoder]
#define OFF_DECXW  58068992u    // 8.39 MB
#define OFF_EO     66457600u    // 4.19 MB
#define OFF_EPROJ  70651904u    // 4.19 MB
#define OFF_DECH   74846208u    // 2.10 MB -> end 76.9 MB

extern "C" void kernel_launch(void* const* d_in, const int* in_sizes, int n_in,
                              void* d_out, int out_size, void* d_ws, size_t ws_size,
                              hipStream_t stream)
{
  const int*   src     = (const int*)d_in[0];
  const int*   tgt     = (const int*)d_in[1];
  const float* enc_emb = (const float*)d_in[2];
  const float* enc_Wih = (const float*)d_in[3];
  const float* enc_Whh = (const float*)d_in[4];
  const float* enc_b   = (const float*)d_in[5];
  const float* attn_W  = (const float*)d_in[6];
  const float* attn_b  = (const float*)d_in[7];
  const float* attn_v  = (const float*)d_in[8];
  const float* dec_emb = (const float*)d_in[9];
  const float* dec_Wih = (const float*)d_in[10];
  const float* dec_Whh = (const float*)d_in[11];
  const float* dec_b   = (const float*)d_in[12];
  const float* out_W   = (const float*)d_in[13];
  const float* out_b   = (const float*)d_in[14];

  char* ws = (char*)d_ws;
  int*      barE   = (int*)(ws + OFF_BARE);
  int*      barD   = (int*)(ws + OFF_BARD);
  unsigned* h16buf = (unsigned*)(ws + OFF_H16);
  float*    cfin   = (float*)(ws + OFF_CFIN);
  float*    vpart  = (float*)(ws + OFF_VPART);
  u16*      A_enc  = (u16*)(ws + OFF_AENC);
  u16*      A_dec  = (u16*)(ws + OFF_ADEC);
  u16*      WihE   = (u16*)(ws + OFF_WIHE);
  u16*      WihD   = (u16*)(ws + OFF_WIHD);
  u16*      Web    = (u16*)(ws + OFF_WEB);
  u16*      WihCp  = (u16*)(ws + OFF_WIHCP);
  u16*      outWb  = (u16*)(ws + OFF_OUTW);
  u16*      encXW  = (u16*)(ws + OFF_ENCXW);
  u16*      eoPb   = (u16*)(ws + OFF_ENCXW);   // alias: encXW dead after encoder
  u16*      decXW  = (u16*)(ws + OFF_DECXW);
  u16*      eo_g   = (u16*)(ws + OFF_EO);
  u16*      eprojb = (u16*)(ws + OFF_EPROJ);
  u16*      dech   = (u16*)(ws + OFF_DECH);

  // zero barriers + h buffers
  (void)hipMemsetAsync(d_ws, 0, OFF_H16 + 65536, stream);

  prep_kernel<<<2048, 256, 0, stream>>>(src, tgt, enc_emb, dec_emb, enc_Wih, dec_Wih,
                                        attn_W, out_W, A_enc, A_dec, WihE, WihD, Web, WihCp, outWb);

  // encXW = emb_src @ enc_Wih^T + enc_b   (4096 x 2048 x 256) -> bf16
  gemm_nt<256, true><<<512, 256, 0, stream>>>(A_enc, WihE, enc_b, (void*)encXW, 4096, 2048);
  // decXW = emb_tgt @ dec_Wih[:, :E]^T + dec_b  (2048 x 2048 x 256) -> bf16
  gemm_nt<256, true><<<256, 256, 0, stream>>>(A_dec, WihD, dec_b, (void*)decXW, 2048, 2048);

  encoder_kernel<<<256, 256, 0, stream>>>(enc_Whh, encXW, h16buf, cfin, eo_g, barE);

  // eproj = enc_out @ W_e^T  (4096 x 512 x 512) -> bf16
  gemm_nt<512, true><<<128, 256, 0, stream>>>(eo_g, Web, nullptr, (void*)eprojb, 4096, 512);
  // eoP = enc_out @ WihCp^T  (4096 x 2048 x 512) -> bf16  (overwrites encXW; permuted cols)
  gemm_nt<512, true><<<512, 256, 0, stream>>>(eo_g, WihCp, nullptr, (void*)eoPb, 4096, 2048);

  decoder_kernel<<<256, 256, 0, stream>>>(dec_Whh, attn_W, attn_b, attn_v,
                                          eprojb, decXW, eoPb, h16buf, cfin,
                                          vpart, dech, barD);

  // out = dec_h @ out_W^T + out_b  (2048 x 32000 x 512) -> f32
  gemm_nt<512, false><<<4000, 256, 0, stream>>>(dech, outWb, out_b, d_out, 2048, 32000);
}

// Round 13
// 1387.508 us; speedup vs baseline: 1.0140x; 1.0140x over previous
//
#include <hip/hip_runtime.h>

#define B_    32
#define SSRC  128
#define STGT  64
#define E_    256
#define H_    512
#define G4    2048
#define V_    32000

typedef unsigned short u16;
typedef short bf16x8 __attribute__((ext_vector_type(8)));
typedef float f32x4 __attribute__((ext_vector_type(4)));

__device__ __forceinline__ u16 f2b(float f) {
  unsigned u = __float_as_uint(f);
  u += 0x7FFFu + ((u >> 16) & 1u);
  return (u16)(u >> 16);
}
__device__ __forceinline__ float b2f(u16 h) {
  return __uint_as_float(((unsigned)h) << 16);
}
__device__ __forceinline__ unsigned pk2(float lo, float hi) {
  return (unsigned)f2b(lo) | (((unsigned)f2b(hi)) << 16);
}
__device__ __forceinline__ float sigm(float x) { return 1.0f / (1.0f + __expf(-x)); }
__device__ __forceinline__ float tanh_(float x) { return 1.0f - 2.0f / (1.0f + __expf(2.0f * x)); }

#if defined(__has_builtin)
#if __has_builtin(__builtin_amdgcn_fdot2_f32_bf16)
#define HAS_DOT2 1
#endif
#endif
#ifdef HAS_DOT2
typedef __bf16 b162 __attribute__((ext_vector_type(2)));
__device__ __forceinline__ float dot2u(unsigned a, unsigned b, float acc) {
  return __builtin_amdgcn_fdot2_f32_bf16(__builtin_bit_cast(b162, a),
                                         __builtin_bit_cast(b162, b), acc, false);
}
#else
__device__ __forceinline__ float dot2u(unsigned a, unsigned b, float acc) {
  acc += __uint_as_float(a << 16) * __uint_as_float(b << 16);
  acc += __uint_as_float(a & 0xffff0000u) * __uint_as_float(b & 0xffff0000u);
  return acc;
}
#endif
__device__ __forceinline__ float dot4(uint4 w, uint4 h, float acc) {
  return dot2u(w.w, h.w, dot2u(w.z, h.z, dot2u(w.y, h.y, dot2u(w.x, h.x, acc))));
}

__device__ __forceinline__ int swz64(int c) {
  return (c & ~3) | ((c & 3) ^ ((c >> 3) & 3));
}

// ---- device-coherent accesses ----
__device__ __forceinline__ uint4 cload4(const void* p) {
  uint4 r;
  asm volatile("global_load_dwordx4 %0, %1, off sc0 sc1\n\ts_waitcnt vmcnt(0)"
               : "=&v"(r) : "v"(p) : "memory");
  return r;
}
__device__ __forceinline__ void cstoref(float* p, float v) {
  asm volatile("global_store_dword %0, %1, off sc0 sc1" :: "v"(p), "v"(v) : "memory");
}
__device__ __forceinline__ void cstoreu(unsigned* p, unsigned v) {
  asm volatile("global_store_dword %0, %1, off sc0 sc1" :: "v"(p), "v"(v) : "memory");
}
__device__ __forceinline__ float cloadf_relaxed(const float* p) {
  return __hip_atomic_load(p, __ATOMIC_RELAXED, __HIP_MEMORY_SCOPE_AGENT);
}

// ---- split barrier: arrive (drain stores + flag) ... optional shadow ... wait ----
__device__ __forceinline__ void arrive(int* flags, int myid, int target) {
  asm volatile("s_waitcnt vmcnt(0)" ::: "memory");
  __syncthreads();
  if (threadIdx.x == 0)
    __hip_atomic_store(flags + myid, target, __ATOMIC_RELAXED, __HIP_MEMORY_SCOPE_AGENT);
}
__device__ __forceinline__ void waitbar(int* flags, int target) {
  if (threadIdx.x < 64) {
    int l = threadIdx.x & 31;
    while (__hip_atomic_load(flags + l, __ATOMIC_RELAXED, __HIP_MEMORY_SCOPE_AGENT) < target)
      __builtin_amdgcn_s_sleep(1);
  }
  __syncthreads();
  asm volatile("" ::: "memory");
}
__device__ __forceinline__ void gbar(int* flags, int myid, int target) {
  arrive(flags, myid, target);
  waitbar(flags, target);
}

// ---------------- prep: gathers + bf16 conversions ----------------
__global__ void prep_kernel(const int* __restrict__ src, const int* __restrict__ tgt,
                            const float* __restrict__ enc_emb, const float* __restrict__ dec_emb,
                            const float* __restrict__ enc_Wih, const float* __restrict__ dec_Wih,
                            const float* __restrict__ attn_W, const float* __restrict__ out_W,
                            u16* __restrict__ A_enc, u16* __restrict__ A_dec,
                            u16* __restrict__ WihE, u16* __restrict__ WihD,
                            u16* __restrict__ Web, u16* __restrict__ WihCp,
                            u16* __restrict__ outWb)
{
  const long n_outw = (long)V_ * H_;
  const long n_aenc = (long)B_ * SSRC * E_;
  const long n_adec = (long)B_ * STGT * E_;
  const long n_wih  = (long)G4 * E_;
  const long n_web  = (long)H_ * H_;
  const long n_wcp  = (long)G4 * H_;
  const long total = n_outw + n_aenc + n_adec + 2 * n_wih + n_web + n_wcp;
  for (long i = (long)blockIdx.x * blockDim.x + threadIdx.x; i < total;
       i += (long)gridDim.x * blockDim.x) {
    long x = i;
    if (x < n_outw) { outWb[x] = f2b(out_W[x]); continue; }
    x -= n_outw;
    if (x < n_aenc) {
      int row = (int)(x >> 8), e = (int)(x & 255);
      A_enc[x] = f2b(enc_emb[(size_t)src[row] * E_ + e]);
      continue;
    }
    x -= n_aenc;
    if (x < n_adec) {
      int row = (int)(x >> 8), e = (int)(x & 255);
      A_dec[x] = f2b(dec_emb[(size_t)tgt[row] * E_ + e]);
      continue;
    }
    x -= n_adec;
    if (x < n_wih) { WihE[x] = f2b(enc_Wih[x]); continue; }
    x -= n_wih;
    if (x < n_wih) {
      int r = (int)(x >> 8), e = (int)(x & 255);
      WihD[x] = f2b(dec_Wih[(size_t)r * 768 + e]);
      continue;
    }
    x -= n_wih;
    if (x < n_web) {
      int d = (int)(x >> 9), k = (int)(x & 511);
      Web[x] = f2b(attn_W[(size_t)d * 1024 + 512 + k]);
      continue;
    }
    x -= n_web;
    {
      // permuted WihC rows: n = gb*64 + gate*16 + jl  ->  orig gate*512 + gb*16 + jl
      int n = (int)(x >> 9), k = (int)(x & 511);
      int gb = n >> 6, gate = (n >> 4) & 3, jl = n & 15;
      int orig = gate * 512 + gb * 16 + jl;
      WihCp[x] = f2b(dec_Wih[(size_t)orig * 768 + 256 + k]);
    }
  }
}

// ---------------- NT GEMM: C[m][n] = sum_k A[m][k]*B[n][k] + bias[n] ----------------
template<int KTOT, bool OBF>
__global__ __launch_bounds__(256, 2) void gemm_nt(
    const u16* __restrict__ A, const u16* __restrict__ Bm,
    const float* __restrict__ bias, void* __restrict__ Cv, int M, int N)
{
  int nbm = M >> 7;
  int bn = blockIdx.x / nbm;
  int bm = blockIdx.x % nbm;
  int w = threadIdx.x >> 6, l = threadIdx.x & 63;
  int wr = w >> 1, wc = w & 1;
  int m0 = bm * 128 + wr * 64, n0 = bn * 128 + wc * 64;
  int lr = l & 15, ko = (l >> 4) * 8;
  f32x4 acc[4][4] = {};
  const u16* Ap = A + (size_t)(m0 + lr) * KTOT + ko;
  const u16* Bp = Bm + (size_t)(n0 + lr) * KTOT + ko;
  for (int k0 = 0; k0 < KTOT; k0 += 32) {
    bf16x8 af[4], bfr[4];
#pragma unroll
    for (int i = 0; i < 4; ++i) af[i] = *(const bf16x8*)(Ap + (size_t)i * 16 * KTOT + k0);
#pragma unroll
    for (int i = 0; i < 4; ++i) bfr[i] = *(const bf16x8*)(Bp + (size_t)i * 16 * KTOT + k0);
#pragma unroll
    for (int i = 0; i < 4; ++i)
#pragma unroll
      for (int j = 0; j < 4; ++j)
        acc[i][j] = __builtin_amdgcn_mfma_f32_16x16x32_bf16(af[i], bfr[j], acc[i][j], 0, 0, 0);
  }
  int rbase = (l >> 4) * 4;
#pragma unroll
  for (int i = 0; i < 4; ++i) {
#pragma unroll
    for (int j = 0; j < 4; ++j) {
      int gn = n0 + j * 16 + lr;
      float bv = bias ? bias[gn] : 0.f;
#pragma unroll
      for (int r = 0; r < 4; ++r) {
        int gm = m0 + i * 16 + rbase + r;
        float v = acc[i][j][r] + bv;
        if (OBF) ((u16*)Cv)[(size_t)gm * N + gn] = f2b(v);
        else     ((float*)Cv)[(size_t)gm * N + gn] = v;
      }
    }
  }
}

// ---- shared z-GEMV: 64 gate-rows x 512 k, bf16, swizzled LDS ----
__device__ __forceinline__ void zgemv64(int tid, const uint4* Wu, const uint4* Hu,
                                        float (*part)[64][4]) {
  int rq = tid >> 4, kq = tid & 15;
  float acc[4][4] = {};
#pragma unroll
  for (int u = 0; u < 4; ++u) {
    int sc = swz64(kq * 4 + u);
    uint4 h0 = Hu[sc], h1 = Hu[64 + sc], h2 = Hu[128 + sc], h3 = Hu[192 + sc];
#pragma unroll
    for (int r = 0; r < 4; ++r) {
      uint4 wv = Wu[(rq * 4 + r) * 64 + sc];
      acc[r][0] = dot4(wv, h0, acc[r][0]);
      acc[r][1] = dot4(wv, h1, acc[r][1]);
      acc[r][2] = dot4(wv, h2, acc[r][2]);
      acc[r][3] = dot4(wv, h3, acc[r][3]);
    }
  }
#pragma unroll
  for (int r = 0; r < 4; ++r) {
    float4 v = {acc[r][0], acc[r][1], acc[r][2], acc[r][3]};
    *(float4*)&part[kq][(rq * 4 + r) ^ (kq & 7)][0] = v;
  }
}

template<typename GrowF>
__device__ __forceinline__ void fillw64(int tid, const float* Wsrc, uint4* Wu, GrowF grow) {
#pragma unroll 4
  for (int i = 0; i < 16; ++i) {
    int idx4 = tid + i * 256;
    int row = idx4 >> 6, c = idx4 & 63;
    const float* s = Wsrc + (size_t)grow(row) * 512 + c * 8;
    float4 a = *(const float4*)s, b4 = *(const float4*)(s + 4);
    uint4 pkv = {pk2(a.x, a.y), pk2(a.z, a.w), pk2(b4.x, b4.y), pk2(b4.z, b4.w)};
    Wu[row * 64 + swz64(c)] = pkv;
  }
}

// ---------------- encoder: persistent, 8 groups x 32 blocks, 1 barrier/step --------
__global__ __launch_bounds__(256, 1) void encoder_kernel(
    const float* __restrict__ enc_Whh, const u16* __restrict__ encXW,
    unsigned* __restrict__ h16buf /* u32 [2][32][256] */,
    float* __restrict__ cfin, u16* __restrict__ eo_g, int* __restrict__ bars)
{
  const int tid = threadIdx.x;
  const int g = blockIdx.x & 7;
  const int gb = blockIdx.x >> 3;
  const int b0 = g * 4;
  const int ds0 = gb * 16;
  int* flags = bars + g * 64;

  __shared__ uint4 encW4[64 * 64];   // 64 KB
  __shared__ uint4 hl16[4 * 64];     // 4 KB
  __shared__ float part[16][64][4];  // 16 KB
  __shared__ float zx[4][64];
  __shared__ float cS[4][16];

  if (tid < 64) cS[tid >> 4][tid & 15] = 0.f;
  fillw64(tid, enc_Whh, encW4, [&](int row) { return (row >> 4) * 512 + ds0 + (row & 15); });
  __syncthreads();

  const int bl_c = tid >> 6, rl_c = tid & 63;
  const int grow_c = (rl_c >> 4) * 512 + ds0 + (rl_c & 15);
  const u16* xwp = encXW + (size_t)(b0 + bl_c) * SSRC * G4 + grow_c;

  for (int t = 0; t < SSRC; ++t) {
    u16 xw = xwp[(size_t)t * G4];  // prefetch: independent of h, overlaps h stage
    // stage h (coherent, 1 dwordx4/thread)
    {
      int row = tid >> 6, c = tid & 63;
      uint4 v = cload4((const uint4*)h16buf + (size_t)(t & 1) * 2048 + (b0 + row) * 64 + c);
      hl16[row * 64 + swz64(c)] = v;
    }
    __syncthreads();
    zgemv64(tid, encW4, hl16, part);
    __syncthreads();
    {
      float z = 0.f;
#pragma unroll
      for (int kq = 0; kq < 16; ++kq) z += part[kq][rl_c ^ (kq & 7)][bl_c];
      z += b2f(xw);
      zx[bl_c][rl_c] = z;
    }
    __syncthreads();
    if (tid < 64) {
      int bl = tid >> 4, jl = tid & 15;
      float iv = zx[bl][jl], fv = zx[bl][16 + jl], gv = zx[bl][32 + jl], ov = zx[bl][48 + jl];
      float cn = sigm(fv) * cS[bl][jl] + sigm(iv) * tanh_(gv);
      float hn = sigm(ov) * tanh_(cn);
      cS[bl][jl] = cn;
      eo_g[((size_t)(b0 + bl) * SSRC + t) * H_ + ds0 + jl] = f2b(hn);
      float hn1 = __shfl_down(hn, 1);
      if ((jl & 1) == 0)
        cstoreu(h16buf + (size_t)((t + 1) & 1) * 8192 + (size_t)(b0 + bl) * 256 + gb * 8 + (jl >> 1),
                pk2(hn, hn1));
    }
    gbar(flags, gb, t + 1);
  }
  if (tid < 64)
    cfin[(size_t)(b0 + (tid >> 4)) * H_ + ds0 + (tid & 15)] = cS[tid >> 4][tid & 15];
}

// ---------------- decoder: persistent, 2 barriers/step ----------------------------
__global__ __launch_bounds__(256, 1) void decoder_kernel(
    const float* __restrict__ dec_Whh, const float* __restrict__ attn_W,
    const float* __restrict__ attn_b, const float* __restrict__ attn_v,
    const u16* __restrict__ eprojb, const u16* __restrict__ decXW,
    const u16* __restrict__ eoPb,
    unsigned* __restrict__ hd16, const float* __restrict__ cfin,
    float* __restrict__ vpart /* f32 [8*32][512] */,
    u16* __restrict__ dech, int* __restrict__ bars)
{
  const int tid = threadIdx.x;
  const int g = blockIdx.x & 7;
  const int gb = blockIdx.x >> 3;
  const int b0 = g * 4;
  const int ds0 = gb * 16;
  int* flags = bars + g * 64;
  int ep_ = 0;

  __shared__ uint4 decW4[64 * 64];   // 64 KB
  __shared__ uint4 Whb4[16 * 64];    // 16 KB
  __shared__ uint4 epL[512][2];      // 16 KB (step-invariant eproj slice)
  __shared__ uint4 hl16[4 * 64];     // 4 KB
  __shared__ float part[16][64][4];  // 16 KB
  __shared__ float partE[8][64][4];  // 8 KB
  __shared__ float scoreS[4][128];   // 2 KB
  __shared__ float aS[4][128];       // 2 KB
  __shared__ float zx[4][64];
  __shared__ float qS[4][16];
  __shared__ float cS[4][16];
  __shared__ float vS[16], bS[16];

  if (tid < 64) cS[tid >> 4][tid & 15] = cfin[(size_t)(b0 + (tid >> 4)) * H_ + ds0 + (tid & 15)];
  if (tid < 16) { vS[tid] = attn_v[ds0 + tid]; bS[tid] = attn_b[ds0 + tid]; }
  fillw64(tid, dec_Whh, decW4, [&](int row) { return (row >> 4) * 512 + ds0 + (row & 15); });
#pragma unroll
  for (int i = 0; i < 4; ++i) {
    int idx4 = tid + i * 256;
    int row = idx4 >> 6, c = idx4 & 63;
    const float* s = attn_W + (size_t)(ds0 + row) * 1024 + c * 8;
    float4 a = *(const float4*)s, b4 = *(const float4*)(s + 4);
    uint4 pkv = {pk2(a.x, a.y), pk2(a.z, a.w), pk2(b4.x, b4.y), pk2(b4.z, b4.w)};
    Whb4[row * 64 + (c ^ (row & 7))] = pkv;
  }
  // eproj slice -> LDS once (step-invariant)
#pragma unroll
  for (int r = 0; r < 2; ++r) {
    int idx = tid + r * 256;
    int b_l = idx >> 7, s = idx & 127;
    const uint4* ep = (const uint4*)(eprojb + (((size_t)(b0 + b_l) * SSRC + s) << 9) + ds0);
    epL[idx][0] = ep[0];
    epL[idx][1] = ep[1];
  }
  // ---- preload this block's static eoP slice into registers (64 KB/block) ----
  // eoPb columns are PERMUTED (WihCp): column gb*64 + gate*16 + jl <-> orig gate*512+gb*16+jl.
  // This block's slice is the contiguous u32 range [gb*32, gb*32+32) of each row. (r7 pairing)
  const int sq = tid >> 5, cp = tid & 31;
  const int n32 = gb * 32 + cp;
  uint4 eor[16];
  {
    const unsigned* eoPu = (const unsigned*)eoPb;
#pragma unroll
    for (int si = 0; si < 16; ++si) {
      int s = sq * 16 + si;
      eor[si].x = eoPu[((size_t)(b0 + 0) * SSRC + s) * 1024 + n32];
      eor[si].y = eoPu[((size_t)(b0 + 1) * SSRC + s) * 1024 + n32];
      eor[si].z = eoPu[((size_t)(b0 + 2) * SSRC + s) * 1024 + n32];
      eor[si].w = eoPu[((size_t)(b0 + 3) * SSRC + s) * 1024 + n32];
    }
  }
  __syncthreads();

  const int bl_c = tid >> 6, rl_c = tid & 63;
  const int grow_c = (rl_c >> 4) * 512 + ds0 + (rl_c & 15);
  const u16* xwp = decXW + (size_t)(b0 + bl_c) * STGT * G4 + grow_c;

  for (int t = 0; t < STGT; ++t) {
    u16 xw = xwp[(size_t)t * G4];  // prefetch bias row (independent of h)
    // ==== Phase 1: stage h; local q-slice; energy d-partials; publish; shadow=zgemv ====
    {
      int row = tid >> 6, c = tid & 63;
      uint4 v = cload4((const uint4*)hd16 + (b0 + row) * 64 + c);
      hl16[row * 64 + swz64(c)] = v;
    }
    __syncthreads();
    {
      int b_l = tid >> 6, d_l = (tid >> 2) & 15, kq4 = tid & 3;
      float acc = 0.f;
#pragma unroll
      for (int u = 0; u < 16; ++u) {
        int c = kq4 * 16 + u;
        acc = dot4(Whb4[d_l * 64 + (c ^ (d_l & 7))], hl16[b_l * 64 + swz64(c)], acc);
      }
      acc += __shfl_xor(acc, 1);
      acc += __shfl_xor(acc, 2);
      if (kq4 == 0) qS[b_l][d_l] = acc + bS[d_l];
    }
    __syncthreads();
    {
      float* vp = vpart + ((size_t)g * 32 + gb) * 512;
#pragma unroll
      for (int r = 0; r < 2; ++r) {
        int idx = tid + r * 256;
        int b_l = idx >> 7;
        uint4 e0 = epL[idx][0], e1 = epL[idx][1];
        float acc = 0.f;
        acc += vS[0]  * tanh_(b2f((u16)(e0.x & 0xffff)) + qS[b_l][0]);
        acc += vS[1]  * tanh_(b2f((u16)(e0.x >> 16))    + qS[b_l][1]);
        acc += vS[2]  * tanh_(b2f((u16)(e0.y & 0xffff)) + qS[b_l][2]);
        acc += vS[3]  * tanh_(b2f((u16)(e0.y >> 16))    + qS[b_l][3]);
        acc += vS[4]  * tanh_(b2f((u16)(e0.z & 0xffff)) + qS[b_l][4]);
        acc += vS[5]  * tanh_(b2f((u16)(e0.z >> 16))    + qS[b_l][5]);
        acc += vS[6]  * tanh_(b2f((u16)(e0.w & 0xffff)) + qS[b_l][6]);
        acc += vS[7]  * tanh_(b2f((u16)(e0.w >> 16))    + qS[b_l][7]);
        acc += vS[8]  * tanh_(b2f((u16)(e1.x & 0xffff)) + qS[b_l][8]);
        acc += vS[9]  * tanh_(b2f((u16)(e1.x >> 16))    + qS[b_l][9]);
        acc += vS[10] * tanh_(b2f((u16)(e1.y & 0xffff)) + qS[b_l][10]);
        acc += vS[11] * tanh_(b2f((u16)(e1.y >> 16))    + qS[b_l][11]);
        acc += vS[12] * tanh_(b2f((u16)(e1.z & 0xffff)) + qS[b_l][12]);
        acc += vS[13] * tanh_(b2f((u16)(e1.z >> 16))    + qS[b_l][13]);
        acc += vS[14] * tanh_(b2f((u16)(e1.w & 0xffff)) + qS[b_l][14]);
        acc += vS[15] * tanh_(b2f((u16)(e1.w >> 16))    + qS[b_l][15]);
        cstoref(vp + idx, acc);
      }
    }
    arrive(flags, gb, ++ep_);
    zgemv64(tid, decW4, hl16, part);   // shadow: hides vpart exchange flight
    waitbar(flags, ep_);

    // ==== Phase 2: gather partials -> scores; softmax; eoP-reg z; gates ====
    {
      int b_l = tid >> 6, s0 = (tid & 63) * 2;
      float a0 = 0.f, a1 = 0.f;
#pragma unroll 8
      for (int j = 0; j < 32; ++j) {
        const float* p = vpart + ((size_t)g * 32 + j) * 512 + b_l * 128 + s0;
        a0 += cloadf_relaxed(p);
        a1 += cloadf_relaxed(p + 1);
      }
      scoreS[b_l][s0] = a0;
      scoreS[b_l][s0 + 1] = a1;
    }
    __syncthreads();
    {
      int w = tid >> 6, lane = tid & 63;
      float s1 = scoreS[w][lane], s2v = scoreS[w][64 + lane];
      float m = fmaxf(s1, s2v);
#pragma unroll
      for (int off = 32; off; off >>= 1) m = fmaxf(m, __shfl_xor(m, off));
      float e1 = __expf(s1 - m), e2 = __expf(s2v - m);
      float sm = e1 + e2;
#pragma unroll
      for (int off = 32; off; off >>= 1) sm += __shfl_xor(sm, off);
      float inv = 1.0f / sm;
      aS[w][lane] = e1 * inv;
      aS[w][64 + lane] = e2 * inv;
    }
    __syncthreads();
    {
      float a0 = 0.f, a1 = 0.f, a2 = 0.f, a3 = 0.f, a4 = 0.f, a5 = 0.f, a6 = 0.f, a7 = 0.f;
#pragma unroll
      for (int si = 0; si < 16; ++si) {
        int s = sq * 16 + si;
        float w0 = aS[0][s], w1 = aS[1][s], w2 = aS[2][s], w3 = aS[3][s];
        unsigned u0 = eor[si].x, u1 = eor[si].y, u2 = eor[si].z, u3 = eor[si].w;
        a0 += w0 * b2f((u16)(u0 & 0xffff)); a1 += w0 * b2f((u16)(u0 >> 16));
        a2 += w1 * b2f((u16)(u1 & 0xffff)); a3 += w1 * b2f((u16)(u1 >> 16));
        a4 += w2 * b2f((u16)(u2 & 0xffff)); a5 += w2 * b2f((u16)(u2 >> 16));
        a6 += w3 * b2f((u16)(u3 & 0xffff)); a7 += w3 * b2f((u16)(u3 >> 16));
      }
      // permuted layout: local row = cp*2 (+1)  (r7 pairing)
      int r0 = cp * 2;
      float4 lo = {a0, a2, a4, a6}, hi = {a1, a3, a5, a7};
      *(float4*)&partE[sq][r0][0] = lo;
      *(float4*)&partE[sq][r0 + 1][0] = hi;
    }
    __syncthreads();
    {
      float z = 0.f;
#pragma unroll
      for (int kq = 0; kq < 16; ++kq) z += part[kq][rl_c ^ (kq & 7)][bl_c];
#pragma unroll
      for (int sq2 = 0; sq2 < 8; ++sq2) z += partE[sq2][rl_c][bl_c];
      z += b2f(xw);
      zx[bl_c][rl_c] = z;
    }
    __syncthreads();
    if (tid < 64) {
      int bl = tid >> 4, jl = tid & 15;
      float iv = zx[bl][jl], fv = zx[bl][16 + jl], gv = zx[bl][32 + jl], ov = zx[bl][48 + jl];
      float cn = sigm(fv) * cS[bl][jl] + sigm(iv) * tanh_(gv);
      float hn = sigm(ov) * tanh_(cn);
      cS[bl][jl] = cn;
      dech[((size_t)(b0 + bl) * STGT + t) * H_ + ds0 + jl] = f2b(hn);
      float hn1 = __shfl_down(hn, 1);
      if ((jl & 1) == 0)
        cstoreu(hd16 + (size_t)(b0 + bl) * 256 + gb * 8 + (jl >> 1), pk2(hn, hn1));
    }
    arrive(flags, gb, ++ep_);
    waitbar(flags, ep_);
  }
}

// ---------------- workspace layout (bytes) ----------------
#define OFF_BARE   0u
#define OFF_BARD   2048u
#define OFF_H16    4096u        // u32 [2][32][256] = 64 KB
#define OFF_CFIN   69632u       // 64 KB
#define OFF_VPART  135168u      // f32 [256][512] = 512 KB
#define OFF_AENC   659456u      // 2 MB
#define OFF_ADEC   2756608u     // 1 MB
#define OFF_WIHE   3805184u     // 1 MB
#define OFF_WIHD   4853760u     // 1 MB
#define OFF_WEB    5902336u     // 512 KB
#define OFF_WIHCP  6426624u     // 2 MB
#define OFF_OUTW   8523776u     // 32.77 MB
#define OFF_ENCXW  41291776u    // 16.78 MB  [aliased by eoP after encoder]
#define OFF_DECXW  58068992u    // 8.39 MB
#define OFF_EO     66457600u    // 4.19 MB
#define OFF_EPROJ  70651904u    // 4.19 MB
#define OFF_DECH   74846208u    // 2.10 MB -> end 76.9 MB

extern "C" void kernel_launch(void* const* d_in, const int* in_sizes, int n_in,
                              void* d_out, int out_size, void* d_ws, size_t ws_size,
                              hipStream_t stream)
{
  const int*   src     = (const int*)d_in[0];
  const int*   tgt     = (const int*)d_in[1];
  const float* enc_emb = (const float*)d_in[2];
  const float* enc_Wih = (const float*)d_in[3];
  const float* enc_Whh = (const float*)d_in[4];
  const float* enc_b   = (const float*)d_in[5];
  const float* attn_W  = (const float*)d_in[6];
  const float* attn_b  = (const float*)d_in[7];
  const float* attn_v  = (const float*)d_in[8];
  const float* dec_emb = (const float*)d_in[9];
  const float* dec_Wih = (const float*)d_in[10];
  const float* dec_Whh = (const float*)d_in[11];
  const float* dec_b   = (const float*)d_in[12];
  const float* out_W   = (const float*)d_in[13];
  const float* out_b   = (const float*)d_in[14];

  char* ws = (char*)d_ws;
  int*      barE   = (int*)(ws + OFF_BARE);
  int*      barD   = (int*)(ws + OFF_BARD);
  unsigned* h16buf = (unsigned*)(ws + OFF_H16);
  float*    cfin   = (float*)(ws + OFF_CFIN);
  float*    vpart  = (float*)(ws + OFF_VPART);
  u16*      A_enc  = (u16*)(ws + OFF_AENC);
  u16*      A_dec  = (u16*)(ws + OFF_ADEC);
  u16*      WihE   = (u16*)(ws + OFF_WIHE);
  u16*      WihD   = (u16*)(ws + OFF_WIHD);
  u16*      Web    = (u16*)(ws + OFF_WEB);
  u16*      WihCp  = (u16*)(ws + OFF_WIHCP);
  u16*      outWb  = (u16*)(ws + OFF_OUTW);
  u16*      encXW  = (u16*)(ws + OFF_ENCXW);
  u16*      eoPb   = (u16*)(ws + OFF_ENCXW);   // alias: encXW dead after encoder
  u16*      decXW  = (u16*)(ws + OFF_DECXW);
  u16*      eo_g   = (u16*)(ws + OFF_EO);
  u16*      eprojb = (u16*)(ws + OFF_EPROJ);
  u16*      dech   = (u16*)(ws + OFF_DECH);

  // zero barriers + h buffers
  (void)hipMemsetAsync(d_ws, 0, OFF_H16 + 65536, stream);

  prep_kernel<<<2048, 256, 0, stream>>>(src, tgt, enc_emb, dec_emb, enc_Wih, dec_Wih,
                                        attn_W, out_W, A_enc, A_dec, WihE, WihD, Web, WihCp, outWb);

  // encXW = emb_src @ enc_Wih^T + enc_b   (4096 x 2048 x 256) -> bf16
  gemm_nt<256, true><<<512, 256, 0, stream>>>(A_enc, WihE, enc_b, (void*)encXW, 4096, 2048);
  // decXW = emb_tgt @ dec_Wih[:, :E]^T + dec_b  (2048 x 2048 x 256) -> bf16
  gemm_nt<256, true><<<256, 256, 0, stream>>>(A_dec, WihD, dec_b, (void*)decXW, 2048, 2048);

  encoder_kernel<<<256, 256, 0, stream>>>(enc_Whh, encXW, h16buf, cfin, eo_g, barE);

  // eproj = enc_out @ W_e^T  (4096 x 512 x 512) -> bf16
  gemm_nt<512, true><<<128, 256, 0, stream>>>(eo_g, Web, nullptr, (void*)eprojb, 4096, 512);
  // eoP = enc_out @ WihCp^T  (4096 x 2048 x 512) -> bf16  (overwrites encXW; permuted cols)
  gemm_nt<512, true><<<512, 256, 0, stream>>>(eo_g, WihCp, nullptr, (void*)eoPb, 4096, 2048);

  decoder_kernel<<<256, 256, 0, stream>>>(dec_Whh, attn_W, attn_b, attn_v,
                                          eprojb, decXW, eoPb, h16buf, cfin,
                                          vpart, dech, barD);

  // out = dec_h @ out_W^T + out_b  (2048 x 32000 x 512) -> f32
  gemm_nt<512, false><<<4000, 256, 0, stream>>>(dech, outWb, out_b, d_out, 2048, 32000);
}